// Round 21
// baseline (205.376 us; speedup 1.0000x reference)
//
#include <hip/hip_runtime.h>

#define NROW 8192
#define INF  512
#define OUTF 256
#define M_ELEM (NROW * OUTF)   // 2,097,152 f32 per output matrix
#define NSTEP 64               // K-steps of 128

typedef __bf16 v8bf __attribute__((ext_vector_type(8)));
typedef __bf16 v4bf __attribute__((ext_vector_type(4)));
typedef float  v4f  __attribute__((ext_vector_type(4)));
typedef float  v2f  __attribute__((ext_vector_type(2)));

__device__ __forceinline__ v8bf cvt_bf8(v4f u0, v4f u1) {
  v8bf v;
  v[0]=(__bf16)u0[0]; v[1]=(__bf16)u0[1]; v[2]=(__bf16)u0[2]; v[3]=(__bf16)u0[3];
  v[4]=(__bf16)u1[0]; v[5]=(__bf16)u1[1]; v[6]=(__bf16)u1[2]; v[7]=(__bf16)u1[3];
  return v;
}

// ---------------------------------------------------------------------------
// Kernel A: seq = feat @ W^T, bf16 MFMA, output in B-fragment-packed layout:
//   elem(m,o) -> (((m>>5)*16 + (o>>4))*64 + ((m>>3)&3)*16 + (o&15))*8 + (m&7)
// ---------------------------------------------------------------------------
__global__ __launch_bounds__(256) void seq_fts_kernel(
    const float* __restrict__ feat, const float* __restrict__ W,
    __bf16* __restrict__ Bp) {
  const int tid  = threadIdx.x;
  const int lane = tid & 63, w = tid >> 6;
  const int llo  = lane & 15, lhi = lane >> 4;
  const int row0 = blockIdx.x * 64;
  const int col0 = w * 64;

  v4f acc[4][4] = {};
#pragma unroll 1
  for (int kb = 0; kb < INF / 32; ++kb) {
    const int kofs = kb * 32 + lhi * 8;
    v8bf a[4], b[4];
#pragma unroll
    for (int i = 0; i < 4; ++i) {
      const float* p = feat + (size_t)(row0 + i * 16 + llo) * INF + kofs;
      a[i] = cvt_bf8(*(const v4f*)p, *(const v4f*)(p + 4));
    }
#pragma unroll
    for (int i = 0; i < 4; ++i) {
      const float* p = W + (size_t)(col0 + i * 16 + llo) * INF + kofs;
      b[i] = cvt_bf8(*(const v4f*)p, *(const v4f*)(p + 4));
    }
#pragma unroll
    for (int ri = 0; ri < 4; ++ri)
#pragma unroll
      for (int ci = 0; ci < 4; ++ci)
        acc[ri][ci] = __builtin_amdgcn_mfma_f32_16x16x32_bf16(
            a[ri], b[ci], acc[ri][ci], 0, 0, 0);
  }
#pragma unroll
  for (int ri = 0; ri < 4; ++ri)
#pragma unroll
    for (int ci = 0; ci < 4; ++ci) {
      const int mf = row0 + ri * 16 + lhi * 4;
      const int o  = col0 + ci * 16 + llo;
      size_t e = (((size_t)(mf >> 5) * 16 + (o >> 4)) * 64 +
                  ((mf >> 3) & 3) * 16 + (o & 15)) * 8 + (mf & 7);
      v4bf v;
      v[0] = (__bf16)acc[ri][ci][0]; v[1] = (__bf16)acc[ri][ci][1];
      v[2] = (__bf16)acc[ri][ci][2]; v[3] = (__bf16)acc[ri][ci][3];
      *(v4bf*)(Bp + e) = v;
    }
}

// ---------------------------------------------------------------------------
// Kernel B: out = prelu(adj @ seq + bias).
// R17 geometry at BK=128: the per-step register set (b[4][2]=32, areg v2f=16,
// acc=32, addr ~20 -> ~105 VGPR) FITS the allocator's observed ~100-VGPR
// comfort zone, so the deep FIFO (all 8 B loads, THEN A(t+1), newest) finally
// survives codegen -- every compute wait drains only B, A(t+1) stays in
// flight across the whole compute phase. LDS halves to 2x32 KB -> TWO blocks
// per CU: while one block is in its write/barrier, the other issues loads
// (duty-cycle gap closed by TLP). B traffic unchanged (same BM=64, dedup'd);
// A extents 512 B (proven ~neutral in R18); NT adj loads; XOR-swizzled LDS.
// ---------------------------------------------------------------------------
__global__ __launch_bounds__(512, 2) void gcn_agg_kernel(
    const float* __restrict__ adjA, const float* __restrict__ adjB,
    const __bf16* __restrict__ Bp, const float* __restrict__ bias,
    const float* __restrict__ prelu_a, float* __restrict__ out) {
  const int tid  = threadIdx.x;
  const int lane = tid & 63, w = tid >> 6;   // wave w -> cols [w*32, w*32+32)
  const int llo  = lane & 15, lhi = lane >> 4;
  const int row0 = blockIdx.x * 64;
  const int z    = blockIdx.y;
  const float* __restrict__ adj = z ? adjB : adjA;

  __shared__ __align__(16) char LdsA[2][32768];   // 2 x (64 rows x 512 B)

  v4f acc[4][2] = {};        // 32 VGPR

  // --- A: 8 rows/wave, one 512 B extent per row (v2f per lane, NT).
  v2f areg[8];
  auto issue_a = [&](int t) {
#pragma unroll
    for (int i = 0; i < 8; ++i) {
      const int r = w * 8 + i;
      const float* src =
          adj + (size_t)(row0 + r) * NROW + t * 128 + (lane << 1);
      areg[i] = __builtin_nontemporal_load((const v2f*)src);
    }
  };
  // swizzled write: lane l's 8 B -> row r, 16B-slot ((l>>1)^key), half (l&1).
  auto write_a = [&](int buf) {
#pragma unroll
    for (int i = 0; i < 8; ++i) {
      const int r   = w * 8 + i;
      const int key = ((r & 15) << 1) | ((r >> 3) & 1);
      const int byt = r * 512 + ((((lane >> 1) ^ key) << 4) | ((lane & 1) << 3));
      *(v2f*)(&LdsA[buf][byt]) = areg[i];
    }
  };

  // --- B fragments for one whole step: [4 kg][2 ci] = 32 VGPR (no dup).
  const __bf16* __restrict__ Bpw = Bp + ((size_t)(w * 2) * 64 + lane) * 8;
  v8bf b[4][2];
  auto load_b_all = [&](int t) {
#pragma unroll
    for (int g = 0; g < 4; ++g)
#pragma unroll
      for (int ci = 0; ci < 2; ++ci)
        b[g][ci] = *(const v8bf*)(
            Bpw + ((size_t)((t * 4 + g) * 16 + ci)) * 512);
  };

  auto compute_g = [&](int buf, int kg) {
    const char* ab = &LdsA[buf][0];
    v8bf af[4];
#pragma unroll
    for (int rt = 0; rt < 4; ++rt) {
      const int r   = rt * 16 + llo;
      const int key = ((r & 15) << 1) | ((r >> 3) & 1);
      const char* base = ab + r * 512;
      const int s0 = kg * 8 + lhi * 2;
      v4f u0 = *(const v4f*)(base + (((s0    ) ^ key) << 4));
      v4f u1 = *(const v4f*)(base + (((s0 + 1) ^ key) << 4));
      af[rt] = cvt_bf8(u0, u1);
    }
#pragma unroll
    for (int ci = 0; ci < 2; ++ci)
#pragma unroll
      for (int rt = 0; rt < 4; ++rt)
        acc[rt][ci] = __builtin_amdgcn_mfma_f32_16x16x32_bf16(
            af[rt], b[kg][ci], acc[rt][ci], 0, 0, 0);
  };

  // prologue: A(0) -> LDS[0]
  issue_a(0);
  asm volatile("s_waitcnt vmcnt(0)" ::: "memory");
  write_a(0);
  asm volatile("s_waitcnt lgkmcnt(0)" ::: "memory");
  __builtin_amdgcn_s_barrier();

#pragma unroll 1
  for (int t = 0; t < NSTEP; ++t) {
    load_b_all(t);                         // 8 B loads, OLDEST in FIFO
    __builtin_amdgcn_sched_barrier(0);
    if (t + 1 < NSTEP) issue_a(t + 1);     // 8 A loads, NEWEST in FIFO
    __builtin_amdgcn_sched_barrier(0);
#pragma unroll
    for (int kg = 0; kg < 4; ++kg)         // waits only B -> A stays in flight
      compute_g(t & 1, kg);
    __builtin_amdgcn_sched_barrier(0);
    if (t + 1 < NSTEP) {
      asm volatile("s_waitcnt vmcnt(0)" ::: "memory");  // only A(t+1) left
      write_a((t + 1) & 1);
      asm volatile("s_waitcnt lgkmcnt(0)" ::: "memory");
    }
    __builtin_amdgcn_s_barrier();
  }

  // epilogue: bias + prelu, direct store
  const float slope = prelu_a[0];
  float* __restrict__ outp = out + (size_t)z * M_ELEM;
#pragma unroll
  for (int ci = 0; ci < 2; ++ci) {
    const int o  = w * 32 + ci * 16 + llo;
    const float bs = bias[o];
#pragma unroll
    for (int rt = 0; rt < 4; ++rt) {
      const int m = row0 + rt * 16 + lhi * 4;
#pragma unroll
      for (int r = 0; r < 4; ++r) {
        float v = acc[rt][ci][r] + bs;
        outp[(size_t)(m + r) * OUTF + o] = v >= 0.f ? v : slope * v;
      }
    }
  }
}

extern "C" void kernel_launch(void* const* d_in, const int* in_sizes, int n_in,
                              void* d_out, int out_size, void* d_ws, size_t ws_size,
                              hipStream_t stream) {
  const float* feat = (const float*)d_in[0];
  const float* adj  = (const float*)d_in[1];
  const float* aug  = (const float*)d_in[2];
  const float* W    = (const float*)d_in[3];
  const float* bias = (const float*)d_in[4];
  const float* pa   = (const float*)d_in[5];
  float* out = (float*)d_out;
  __bf16* Bp = (__bf16*)d_ws;                    // 4 MB packed seq_fts

  seq_fts_kernel<<<dim3(NROW / 64), 256, 0, stream>>>(feat, W, Bp);
  gcn_agg_kernel<<<dim3(NROW / 64, 2), 512, 0, stream>>>(
      adj, aug, Bp, bias, pa, out);
}

// Round 22
// 179.210 us; speedup vs baseline: 1.1460x; 1.1460x over previous
//
#include <hip/hip_runtime.h>

#define NROW 8192
#define INF  512
#define OUTF 256
#define M_ELEM (NROW * OUTF)   // 2,097,152 f32 per output matrix
#define NSTEP 64               // K-steps of 128

typedef __bf16 v8bf __attribute__((ext_vector_type(8)));
typedef __bf16 v4bf __attribute__((ext_vector_type(4)));
typedef float  v4f  __attribute__((ext_vector_type(4)));
typedef float  v2f  __attribute__((ext_vector_type(2)));

__device__ __forceinline__ v8bf cvt_bf8(v4f u0, v4f u1) {
  v8bf v;
  v[0]=(__bf16)u0[0]; v[1]=(__bf16)u0[1]; v[2]=(__bf16)u0[2]; v[3]=(__bf16)u0[3];
  v[4]=(__bf16)u1[0]; v[5]=(__bf16)u1[1]; v[6]=(__bf16)u1[2]; v[7]=(__bf16)u1[3];
  return v;
}

// ---------------------------------------------------------------------------
// Kernel A: seq = feat @ W^T, bf16 MFMA, output in B-fragment-packed layout:
//   elem(m,o) -> (((m>>5)*16 + (o>>4))*64 + ((m>>3)&3)*16 + (o&15))*8 + (m&7)
// ---------------------------------------------------------------------------
__global__ __launch_bounds__(256) void seq_fts_kernel(
    const float* __restrict__ feat, const float* __restrict__ W,
    __bf16* __restrict__ Bp) {
  const int tid  = threadIdx.x;
  const int lane = tid & 63, w = tid >> 6;
  const int llo  = lane & 15, lhi = lane >> 4;
  const int row0 = blockIdx.x * 64;
  const int col0 = w * 64;

  v4f acc[4][4] = {};
#pragma unroll 1
  for (int kb = 0; kb < INF / 32; ++kb) {
    const int kofs = kb * 32 + lhi * 8;
    v8bf a[4], b[4];
#pragma unroll
    for (int i = 0; i < 4; ++i) {
      const float* p = feat + (size_t)(row0 + i * 16 + llo) * INF + kofs;
      a[i] = cvt_bf8(*(const v4f*)p, *(const v4f*)(p + 4));
    }
#pragma unroll
    for (int i = 0; i < 4; ++i) {
      const float* p = W + (size_t)(col0 + i * 16 + llo) * INF + kofs;
      b[i] = cvt_bf8(*(const v4f*)p, *(const v4f*)(p + 4));
    }
#pragma unroll
    for (int ri = 0; ri < 4; ++ri)
#pragma unroll
      for (int ci = 0; ci < 4; ++ci)
        acc[ri][ci] = __builtin_amdgcn_mfma_f32_16x16x32_bf16(
            a[ri], b[ci], acc[ri][ci], 0, 0, 0);
  }
#pragma unroll
  for (int ri = 0; ri < 4; ++ri)
#pragma unroll
    for (int ci = 0; ci < 4; ++ci) {
      const int mf = row0 + ri * 16 + lhi * 4;
      const int o  = col0 + ci * 16 + llo;
      size_t e = (((size_t)(mf >> 5) * 16 + (o >> 4)) * 64 +
                  ((mf >> 3) & 3) * 16 + (o & 15)) * 8 + (mf & 7);
      v4bf v;
      v[0] = (__bf16)acc[ri][ci][0]; v[1] = (__bf16)acc[ri][ci][1];
      v[2] = (__bf16)acc[ri][ci][2]; v[3] = (__bf16)acc[ri][ci][3];
      *(v4bf*)(Bp + e) = v;
    }
}

// ---------------------------------------------------------------------------
// Kernel B: out = prelu(adj @ seq + bias).
// CROSS-STEP B double-buffer: B(t+1) and A(t+1) are issued during step t;
// the step-end vmcnt(0) (required for write_a anyway) retires them for free.
// Step t+1's compute then has ZERO load waits -- its b regs landed a full
// step earlier, so the compiler's auto-wait is vmcnt(>=16), a no-op against
// the newly issued B(t+2)/A(t+2). One latency exposure per step (the drain)
// instead of ~9 serialized B-chunk waits (R17..R21's residual). Sink-proof:
// even if codegen sinks B(t+2) loads into iteration t+1, they still precede
// their consumption (step t+2) by a full barrier.
// BK=128 so both B sets fit the 128-VGPR/16-wave budget: bX+bY=64, areg=16,
// acc=32, addr ~16. BM=64, 8 waves, col-dedup'd; LDS 2x32 KB -> 2 blocks/CU.
// ---------------------------------------------------------------------------
__global__ __launch_bounds__(512, 2) void gcn_agg_kernel(
    const float* __restrict__ adjA, const float* __restrict__ adjB,
    const __bf16* __restrict__ Bp, const float* __restrict__ bias,
    const float* __restrict__ prelu_a, float* __restrict__ out) {
  const int tid  = threadIdx.x;
  const int lane = tid & 63, w = tid >> 6;   // wave w -> cols [w*32, w*32+32)
  const int llo  = lane & 15, lhi = lane >> 4;
  const int row0 = blockIdx.x * 64;
  const int z    = blockIdx.y;
  const float* __restrict__ adj = z ? adjB : adjA;

  __shared__ __align__(16) char LdsA[2][32768];   // 2 x (64 rows x 512 B)

  v4f acc[4][2] = {};        // 32 VGPR

  // --- A: 8 rows/wave, one 512 B extent per row (v2f per lane, NT).
  v2f areg[8];
  auto issue_a = [&](int t) {
#pragma unroll
    for (int i = 0; i < 8; ++i) {
      const int r = w * 8 + i;
      const float* src =
          adj + (size_t)(row0 + r) * NROW + t * 128 + (lane << 1);
      areg[i] = __builtin_nontemporal_load((const v2f*)src);
    }
  };
  // swizzled write: lane l's 8 B -> row r, 16B-slot ((l>>1)^key), half (l&1).
  auto write_a = [&](int buf) {
#pragma unroll
    for (int i = 0; i < 8; ++i) {
      const int r   = w * 8 + i;
      const int key = ((r & 15) << 1) | ((r >> 3) & 1);
      const int byt = r * 512 + ((((lane >> 1) ^ key) << 4) | ((lane & 1) << 3));
      *(v2f*)(&LdsA[buf][byt]) = areg[i];
    }
  };

  // --- B fragments: [4 kg][2 ci] = 32 VGPR per set (col-dedup'd).
  const __bf16* __restrict__ Bpw = Bp + ((size_t)(w * 2) * 64 + lane) * 8;
  auto issue_b = [&](int t, v8bf (&b)[4][2]) {
#pragma unroll
    for (int g = 0; g < 4; ++g)
#pragma unroll
      for (int ci = 0; ci < 2; ++ci)
        b[g][ci] = *(const v8bf*)(
            Bpw + ((size_t)((t * 4 + g) * 16 + ci)) * 512);
  };

  auto compute = [&](int buf, v8bf (&b)[4][2]) {
    const char* ab = &LdsA[buf][0];
#pragma unroll
    for (int kg = 0; kg < 4; ++kg) {
      v8bf af[4];
#pragma unroll
      for (int rt = 0; rt < 4; ++rt) {
        const int r   = rt * 16 + llo;
        const int key = ((r & 15) << 1) | ((r >> 3) & 1);
        const char* base = ab + r * 512;
        const int s0 = kg * 8 + lhi * 2;
        v4f u0 = *(const v4f*)(base + (((s0    ) ^ key) << 4));
        v4f u1 = *(const v4f*)(base + (((s0 + 1) ^ key) << 4));
        af[rt] = cvt_bf8(u0, u1);
      }
#pragma unroll
      for (int ci = 0; ci < 2; ++ci)
#pragma unroll
        for (int rt = 0; rt < 4; ++rt)
          acc[rt][ci] = __builtin_amdgcn_mfma_f32_16x16x32_bf16(
              af[rt], b[kg][ci], acc[rt][ci], 0, 0, 0);
    }
  };

  v8bf bX[4][2], bY[4][2];

  // prologue: B(0)->bX and A(0) in one burst; drain; A(0)->LDS0.
  issue_b(0, bX);
  issue_a(0);
  asm volatile("s_waitcnt vmcnt(0)" ::: "memory");
  write_a(0);
  asm volatile("s_waitcnt lgkmcnt(0)" ::: "memory");
  __builtin_amdgcn_s_barrier();

#pragma unroll 1
  for (int t = 0; t < NSTEP; t += 2) {
    // ---- step t: compute(LDS0, bX); prefetch B(t+1)->bY, A(t+1)
    {
      const int tn = (t + 1 < NSTEP) ? t + 1 : NSTEP - 1;
      issue_b(tn, bY);
      issue_a(tn);
    }
    __builtin_amdgcn_sched_barrier(0);
    compute(0, bX);                        // bX landed last step: no waits
    __builtin_amdgcn_sched_barrier(0);
    asm volatile("s_waitcnt vmcnt(0)" ::: "memory");   // B(t+1)+A(t+1) landed
    write_a(1);
    asm volatile("s_waitcnt lgkmcnt(0)" ::: "memory");
    __builtin_amdgcn_s_barrier();
    // ---- step t+1: compute(LDS1, bY); prefetch B(t+2)->bX, A(t+2)
    {
      const int tn = (t + 2 < NSTEP) ? t + 2 : NSTEP - 1;
      issue_b(tn, bX);
      issue_a(tn);
    }
    __builtin_amdgcn_sched_barrier(0);
    compute(1, bY);
    __builtin_amdgcn_sched_barrier(0);
    asm volatile("s_waitcnt vmcnt(0)" ::: "memory");
    write_a(0);
    asm volatile("s_waitcnt lgkmcnt(0)" ::: "memory");
    __builtin_amdgcn_s_barrier();
  }

  // epilogue: bias + prelu, direct store
  const float slope = prelu_a[0];
  float* __restrict__ outp = out + (size_t)z * M_ELEM;
#pragma unroll
  for (int ci = 0; ci < 2; ++ci) {
    const int o  = w * 32 + ci * 16 + llo;
    const float bs = bias[o];
#pragma unroll
    for (int rt = 0; rt < 4; ++rt) {
      const int m = row0 + rt * 16 + lhi * 4;
#pragma unroll
      for (int r = 0; r < 4; ++r) {
        float v = acc[rt][ci][r] + bs;
        outp[(size_t)(m + r) * OUTF + o] = v >= 0.f ? v : slope * v;
      }
    }
  }
}

extern "C" void kernel_launch(void* const* d_in, const int* in_sizes, int n_in,
                              void* d_out, int out_size, void* d_ws, size_t ws_size,
                              hipStream_t stream) {
  const float* feat = (const float*)d_in[0];
  const float* adj  = (const float*)d_in[1];
  const float* aug  = (const float*)d_in[2];
  const float* W    = (const float*)d_in[3];
  const float* bias = (const float*)d_in[4];
  const float* pa   = (const float*)d_in[5];
  float* out = (float*)d_out;
  __bf16* Bp = (__bf16*)d_ws;                    // 4 MB packed seq_fts

  seq_fts_kernel<<<dim3(NROW / 64), 256, 0, stream>>>(feat, W, Bp);
  gcn_agg_kernel<<<dim3(NROW / 64, 2), 512, 0, stream>>>(
      adj, aug, Bp, bias, pa, out);
}